// Round 15
// baseline (44.313 us; speedup 1.0000x reference)
//
#include <hip/hip_runtime.h>

#define N2 8192
#define NHALF 4096
#define DDIM 128
#define NCHUNK 32
#define CPC 256           // cols per chunk
#define NT 4              // B-tiles per chunk (256/64)
#define LN2F 0.69314718055994530942f
// SCALEF = sqrt(log2(e)/T) with T=0.5 -> sqrt(2.8853900817779268)
#define SCALEF 1.6986436f

typedef __attribute__((ext_vector_type(8))) short bf8_t;   // 8 bf16 = 4 VGPR
typedef __attribute__((ext_vector_type(4))) float f4_t;    // MFMA C/D frag

__device__ __forceinline__ float fexp2(float x) { return __builtin_amdgcn_exp2f(x); }
__device__ __forceinline__ float flog2(float x) { return __builtin_amdgcn_logf(x); }

__device__ __forceinline__ unsigned short f2bf(float f) {
  unsigned int x = __float_as_uint(f);
  x += 0x7fffu + ((x >> 16) & 1u);   // RNE (no NaN inputs here)
  return (unsigned short)(x >> 16);
}
__device__ __forceinline__ float bf2f(unsigned short h) {
  return __uint_as_float(((unsigned int)h) << 16);
}

// ---------------------------------------------------------------------------
// Kernel 1: normalize rows, scale by sqrt(log2e/T), store bf16 u[8192][128];
// also store dhat[i] = sum_k u_bf16[i][k]^2 (diag logit). Unchanged (passing).
// ---------------------------------------------------------------------------
__global__ __launch_bounds__(256) void knorm(const float* __restrict__ zi,
                                             const float* __restrict__ zj,
                                             unsigned short* __restrict__ u,
                                             float* __restrict__ dhat) {
  const int lane = threadIdx.x & 63;
  const int row = blockIdx.x * 4 + (threadIdx.x >> 6);
  const float* src = (row < NHALF) ? (zi + (size_t)row * DDIM)
                                   : (zj + (size_t)(row - NHALF) * DDIM);
  float2 x = *(const float2*)(src + lane * 2);
  float ss = x.x * x.x + x.y * x.y;
#pragma unroll
  for (int m = 32; m; m >>= 1) ss += __shfl_xor(ss, m);
  float scale = SCALEF / fmaxf(sqrtf(ss), 1e-8f);  // eps clamp as in reference
  unsigned short b0 = f2bf(x.x * scale);
  unsigned short b1 = f2bf(x.y * scale);
  *(unsigned int*)(u + (size_t)row * DDIM + lane * 2) =
      (unsigned int)b0 | ((unsigned int)b1 << 16);
  float f0 = bf2f(b0), f1 = bf2f(b1);
  float dd = f0 * f0 + f1 * f1;
#pragma unroll
  for (int m = 32; m; m >>= 1) dd += __shfl_xor(dd, m);
  if (lane == 0) dhat[row] = dd;
}

// ---------------------------------------------------------------------------
// Kernel 2: fused sim GEMM + per-row sum of exp2 (logits bounded, no max).
// r14 post-mortem: clean codegen (no spill) at ksim~28.5us, but only 2 WGs/CU
// (2 waves/SIMD) -> intra-wave dep chains + barrier lockstep uncovered.
// r15 = r14 with ONE change: NCHUNK 16->32 (grid 512->1024 WGs) -> 3 WGs/CU
// resident (LDS 48KB 3-ring; VGPR ~150 -> 3 waves/SIMD). Co-resident WGs at
// staggered phases cover each other's stalls (m114 co-scheduling).
// Mechanics (validated r11-r14): B staged via lane-contiguous 1KB
// global_load_lds with involution pre-swizzle (unit du of col c at du^(c&7));
// 3-ring, depth-2 prefetch, ONE barrier/tile, counted vmcnt (never 0 in
// steady state); A gathered once from global, pinned; main loop unroll 1.
// grid = 32 rowblocks x 32 chunks = 1024 WGs.
// ---------------------------------------------------------------------------
__global__ __launch_bounds__(256) void ksim(const unsigned short* __restrict__ u,
                                            float* __restrict__ Lp) {
  __shared__ short Bls[24576];  // 48 KB = 3 ring bufs x 16 KB
  const int tid = threadIdx.x;
  const int lane = tid & 63;
  const int w = tid >> 6;
  const int rb = blockIdx.x >> 5;          // 0..31
  const int chunk = blockIdx.x & 31;       // 0..31
  const int lr = lane & 15, lq = lane >> 4;
  const int rowbase = rb * 256 + w * 64;   // wave's private 64 rows
  const int colbase = chunk * CPC;

  // ---- A: 64 rows per wave, gathered once from global, pinned.
  bf8_t a[4][4];
#pragma unroll
  for (int s = 0; s < 4; s++)
#pragma unroll
    for (int kc = 0; kc < 4; kc++)
      a[s][kc] = *(const bf8_t*)(u + (size_t)(rowbase + s * 16 + lr) * DDIM +
                                 kc * 32 + lq * 8);
#pragma unroll
  for (int s = 0; s < 4; s++)
#pragma unroll
    for (int kc = 0; kc < 4; kc++)
      asm volatile("" : "+v"(a[s][kc]));

  f4_t L[4];
#pragma unroll
  for (int s = 0; s < 4; s++) L[s] = (f4_t){0.f, 0.f, 0.f, 0.f};

  // ---- B stage: 64-col tile = 16KB = 16 linear 1KB DMAs (4 per wave).
  // LDS unit U holds global du = (U&15)^(col&7); lane l of DMA j covers
  // unit j*64+l -> col = j*4+lq, src du = lr^(4*(j&1)+lq).
  auto STAGE = [&](int t) {
    const int bufo = (t % 3) * 8192;                 // shorts
#pragma unroll
    for (int i = 0; i < 4; i++) {
      const int j = w * 4 + i;
      const int col_local = j * 4 + lq;
      const int sdu = lr ^ (4 * (i & 1) + lq);
      const unsigned short* src =
          u + (size_t)(colbase + t * 64 + col_local) * DDIM + sdu * 8;
      short* dst = &Bls[bufo + j * 512];             // wave-uniform, linear
      __builtin_amdgcn_global_load_lds(
          (const __attribute__((address_space(1))) unsigned int*)src,
          (__attribute__((address_space(3))) unsigned int*)dst, 16, 0, 0);
    }
  };

  auto COMP = [&](int t) {
    const short* P = &Bls[(t % 3) * 8192];
#pragma unroll
    for (int g = 0; g < 4; g++) {
      bf8_t bv[4];
#pragma unroll
      for (int kc = 0; kc < 4; kc++)
        bv[kc] = *(const bf8_t*)&P[((g * 16 + lr) * 16 +
                                    ((kc * 4 + lq) ^ (lr & 7))) * 8];
      f4_t acc[4];
#pragma unroll
      for (int s = 0; s < 4; s++) acc[s] = (f4_t){0.f, 0.f, 0.f, 0.f};
#pragma unroll
      for (int kc = 0; kc < 4; kc++)
#pragma unroll
        for (int s = 0; s < 4; s++)
          acc[s] = __builtin_amdgcn_mfma_f32_16x16x32_bf16(a[s][kc], bv[kc], acc[s], 0, 0, 0);
#pragma unroll
      for (int s = 0; s < 4; s++)
#pragma unroll
        for (int r = 0; r < 4; r++) L[s][r] += fexp2(acc[s][r]);
    }
  };

  // depth-2 prefetch, 1 barrier/tile, counted vmcnt (never 0 until the end)
  STAGE(0);
  STAGE(1);
#pragma unroll 1
  for (int t = 0; t < NT; ++t) {
    if (t < NT - 1) {
      asm volatile("s_waitcnt vmcnt(4)" ::: "memory");   // my tile-t DMAs done
    } else {
      asm volatile("s_waitcnt vmcnt(0)" ::: "memory");
    }
    __builtin_amdgcn_sched_barrier(0);
    __builtin_amdgcn_s_barrier();                        // all waves' tile-t done
    __builtin_amdgcn_sched_barrier(0);
    COMP(t);
    if (t + 2 < NT) STAGE(t + 2);
  }

  // reduce across the 16 column-lanes (lanes sharing lq hold the same rows)
#pragma unroll
  for (int s = 0; s < 4; s++)
#pragma unroll
    for (int r = 0; r < 4; r++) {
      float v = L[s][r];
      v += __shfl_xor(v, 1); v += __shfl_xor(v, 2);
      v += __shfl_xor(v, 4); v += __shfl_xor(v, 8);
      if (lr == 0)
        Lp[(size_t)chunk * N2 + rowbase + s * 16 + lq * 4 + r] = v;
    }
}

// ---------------------------------------------------------------------------
// Kernel 3: per-row loss. L_i = sum of 32 partials - exp2(dhat_i);
// target logit from direct bf16 dot; loss_i = ln2*(log2(L_i) - target).
// ---------------------------------------------------------------------------
__global__ __launch_bounds__(256) void krow(const unsigned short* __restrict__ u,
                                            const float* __restrict__ dhat,
                                            const float* __restrict__ Lp,
                                            float* __restrict__ bsum) {
  const int i = blockIdx.x * 256 + threadIdx.x;
  float L = 0.f;
#pragma unroll
  for (int c = 0; c < NCHUNK; c++) L += Lp[(size_t)c * N2 + i];
  L -= fexp2(dhat[i]);   // remove self-similarity term (== diag set to -inf)

  const int j = (i + NHALF) & (N2 - 1);  // positive-pair label
  const unsigned int* ui = (const unsigned int*)(u + (size_t)i * DDIM);
  const unsigned int* uj = (const unsigned int*)(u + (size_t)j * DDIM);
  float dot = 0.f;
#pragma unroll
  for (int k = 0; k < DDIM / 2; k++) {
    unsigned int av = ui[k], bv = uj[k];
    dot += __uint_as_float(av << 16) * __uint_as_float(bv << 16) +
           __uint_as_float(av & 0xffff0000u) * __uint_as_float(bv & 0xffff0000u);
  }
  float loss = LN2F * (flog2(L) - dot);

#pragma unroll
  for (int m = 32; m; m >>= 1) loss += __shfl_xor(loss, m);
  __shared__ float sred[4];
  if ((threadIdx.x & 63) == 0) sred[threadIdx.x >> 6] = loss;
  __syncthreads();
  if (threadIdx.x == 0) bsum[blockIdx.x] = sred[0] + sred[1] + sred[2] + sred[3];
}

// ---------------------------------------------------------------------------
// Kernel 4: final mean over the 32 block partials.
// ---------------------------------------------------------------------------
__global__ void kfinal(const float* __restrict__ bsum, float* __restrict__ out) {
  float v = (threadIdx.x < N2 / 256) ? bsum[threadIdx.x] : 0.f;
#pragma unroll
  for (int m = 32; m; m >>= 1) v += __shfl_xor(v, m);
  if (threadIdx.x == 0) out[0] = v * (1.0f / N2);
}

// ---------------------------------------------------------------------------
// ws layout: u bf16 [8192][128] (2 MB) | dhat f32[8192] (32 KB) |
//            Lp f32[NCHUNK][8192] (1 MB) | bsum f32[32]  -> ~3.03 MB total
// ---------------------------------------------------------------------------
extern "C" void kernel_launch(void* const* d_in, const int* in_sizes, int n_in,
                              void* d_out, int out_size, void* d_ws, size_t ws_size,
                              hipStream_t stream) {
  const float* zi = (const float*)d_in[0];
  const float* zj = (const float*)d_in[1];
  char* ws = (char*)d_ws;
  unsigned short* u = (unsigned short*)ws;
  float* dhat = (float*)(ws + (size_t)N2 * DDIM * 2);
  float* Lp = (float*)(ws + (size_t)N2 * DDIM * 2 + (size_t)N2 * 4);
  float* bsum = (float*)(ws + (size_t)N2 * DDIM * 2 + (size_t)N2 * 4 +
                         (size_t)NCHUNK * N2 * 4);
  float* out = (float*)d_out;

  hipLaunchKernelGGL(knorm, dim3(N2 / 4), dim3(256), 0, stream, zi, zj, u, dhat);
  hipLaunchKernelGGL(ksim, dim3((N2 / 256) * NCHUNK), dim3(256), 0, stream, u, Lp);
  hipLaunchKernelGGL(krow, dim3(N2 / 256), dim3(256), 0, stream, u, dhat, Lp, bsum);
  hipLaunchKernelGGL(kfinal, dim3(1), dim3(64), 0, stream, bsum, out);
}

// Round 17
// 40.344 us; speedup vs baseline: 1.0984x; 1.0984x over previous
//
#include <hip/hip_runtime.h>

#define N2 8192
#define NHALF 4096
#define DDIM 128
#define NCHUNK 16
#define CPC 512           // cols per chunk
#define NT 8              // B-tiles per chunk (512/64)
#define LN2F 0.69314718055994530942f
// SCALEF = sqrt(log2(e)/T) with T=0.5 -> sqrt(2.8853900817779268)
#define SCALEF 1.6986436f

typedef __attribute__((ext_vector_type(8))) short bf8_t;   // 8 bf16 = 4 VGPR
typedef __attribute__((ext_vector_type(4))) float f4_t;    // MFMA C/D frag

__device__ __forceinline__ float fexp2(float x) { return __builtin_amdgcn_exp2f(x); }
__device__ __forceinline__ float flog2(float x) { return __builtin_amdgcn_logf(x); }

__device__ __forceinline__ unsigned short f2bf(float f) {
  unsigned int x = __float_as_uint(f);
  x += 0x7fffu + ((x >> 16) & 1u);   // RNE (no NaN inputs here)
  return (unsigned short)(x >> 16);
}
__device__ __forceinline__ float bf2f(unsigned short h) {
  return __uint_as_float(((unsigned int)h) << 16);
}

// ---------------------------------------------------------------------------
// Kernel 1: normalize rows, scale by sqrt(log2e/T), store bf16 u[8192][128];
// also store dhat[i] = sum_k u_bf16[i][k]^2 (diag logit). Unchanged (passing).
// ---------------------------------------------------------------------------
__global__ __launch_bounds__(256) void knorm(const float* __restrict__ zi,
                                             const float* __restrict__ zj,
                                             unsigned short* __restrict__ u,
                                             float* __restrict__ dhat) {
  const int lane = threadIdx.x & 63;
  const int row = blockIdx.x * 4 + (threadIdx.x >> 6);
  const float* src = (row < NHALF) ? (zi + (size_t)row * DDIM)
                                   : (zj + (size_t)(row - NHALF) * DDIM);
  float2 x = *(const float2*)(src + lane * 2);
  float ss = x.x * x.x + x.y * x.y;
#pragma unroll
  for (int m = 32; m; m >>= 1) ss += __shfl_xor(ss, m);
  float scale = SCALEF / fmaxf(sqrtf(ss), 1e-8f);  // eps clamp as in reference
  unsigned short b0 = f2bf(x.x * scale);
  unsigned short b1 = f2bf(x.y * scale);
  *(unsigned int*)(u + (size_t)row * DDIM + lane * 2) =
      (unsigned int)b0 | ((unsigned int)b1 << 16);
  float f0 = bf2f(b0), f1 = bf2f(b1);
  float dd = f0 * f0 + f1 * f1;
#pragma unroll
  for (int m = 32; m; m >>= 1) dd += __shfl_xor(dd, m);
  if (lane == 0) dhat[row] = dd;
}

// ---------------------------------------------------------------------------
// Kernel 2: fused sim GEMM + per-row sum of exp2 (logits bounded, no max).
// r16 post-mortem: barrier-free+byte-efficient is geometrically impossible
// (shared B requires a barrier); r16's private-rows+private-cols covered only
// 1/4 of the tile (absmax 1.34). REVERTED to r14's proven chassis.
// r17 change (single axis): in-tile PHASE INTERLEAVE (T3/T4-lite + T5).
// r14 ran its pipes back-to-back (ksim ~= sum of pipe floors ~25us, m233's
// 2-phase stall). Here each tile's COMP is 4 phases: {4x ds_read | issue 1
// DMA of STAGE(t+2) | sched_barrier | setprio(1) 16 MFMA setprio(0) |
// 16 exp2}. Barrier/vmcnt placement BYTE-IDENTICAL to r14 (1 counted
// vmcnt(4) + 1 s_barrier per tile) -> correctness argument unchanged.
// Staging mechanics validated r11-r14: lane-contiguous 1KB global_load_lds,
// involution pre-swizzle (16B-unit du of col c at du^(c&7)), 3-ring 48KB,
// depth-2 prefetch, A gathered once + pinned, main loop unroll 1.
// grid = 32 rowblocks x 16 chunks = 512 WGs; 2 WG/CU.
// ---------------------------------------------------------------------------
__global__ __launch_bounds__(256) void ksim(const unsigned short* __restrict__ u,
                                            float* __restrict__ Lp) {
  __shared__ short Bls[24576];  // 48 KB = 3 ring bufs x 16 KB
  const int tid = threadIdx.x;
  const int lane = tid & 63;
  const int w = tid >> 6;
  const int rb = blockIdx.x >> 4;          // 0..31
  const int chunk = blockIdx.x & 15;       // 0..15
  const int lr = lane & 15, lq = lane >> 4;
  const int rowbase = rb * 256 + w * 64;   // wave's private 64 rows
  const int colbase = chunk * CPC;

  // ---- A: 64 rows per wave, gathered once from global, pinned.
  bf8_t a[4][4];
#pragma unroll
  for (int s = 0; s < 4; s++)
#pragma unroll
    for (int kc = 0; kc < 4; kc++)
      a[s][kc] = *(const bf8_t*)(u + (size_t)(rowbase + s * 16 + lr) * DDIM +
                                 kc * 32 + lq * 8);
#pragma unroll
  for (int s = 0; s < 4; s++)
#pragma unroll
    for (int kc = 0; kc < 4; kc++)
      asm volatile("" : "+v"(a[s][kc]));   // forces drain of A loads

  f4_t L[4];
#pragma unroll
  for (int s = 0; s < 4; s++) L[s] = (f4_t){0.f, 0.f, 0.f, 0.f};

  // ---- B stage (prologue form): 64-col tile = 16KB = 16 linear 1KB DMAs
  // (4 per wave). LDS unit U holds global du = (U&15)^(col&7).
  auto STAGE = [&](int t) {
#pragma unroll
    for (int i = 0; i < 4; i++) {
      const int j = w * 4 + i;
      const int col_local = j * 4 + lq;
      const int sdu = lr ^ (4 * (i & 1) + lq);
      const unsigned short* src =
          u + (size_t)(colbase + t * 64 + col_local) * DDIM + sdu * 8;
      short* dst = &Bls[(t % 3) * 8192 + j * 512];
      __builtin_amdgcn_global_load_lds(
          (const __attribute__((address_space(1))) unsigned int*)src,
          (__attribute__((address_space(3))) unsigned int*)dst, 16, 0, 0);
    }
  };

  // ---- interleaved compute: COMP(t) in 4 phases, one STAGE(t+2)-DMA each.
  auto COMPI = [&](int t, bool do_stage) {
    const short* P = &Bls[(t % 3) * 8192];
#pragma unroll
    for (int g = 0; g < 4; g++) {
      bf8_t bv[4];
#pragma unroll
      for (int kc = 0; kc < 4; kc++)
        bv[kc] = *(const bf8_t*)&P[((g * 16 + lr) * 16 +
                                    ((kc * 4 + lq) ^ (lr & 7))) * 8];
      if (do_stage) {                       // DMA #g of tile t+2
        const int j = w * 4 + g;
        const int col_local = j * 4 + lq;
        const int sdu = lr ^ (4 * (g & 1) + lq);
        const unsigned short* src =
            u + (size_t)(colbase + (t + 2) * 64 + col_local) * DDIM + sdu * 8;
        short* dst = &Bls[((t + 2) % 3) * 8192 + j * 512];
        __builtin_amdgcn_global_load_lds(
            (const __attribute__((address_space(1))) unsigned int*)src,
            (__attribute__((address_space(3))) unsigned int*)dst, 16, 0, 0);
      }
      __builtin_amdgcn_sched_barrier(0);    // pin: reads+DMA issued pre-MFMA
      f4_t acc[4];
#pragma unroll
      for (int s = 0; s < 4; s++) acc[s] = (f4_t){0.f, 0.f, 0.f, 0.f};
      __builtin_amdgcn_s_setprio(1);
#pragma unroll
      for (int kc = 0; kc < 4; kc++)
#pragma unroll
        for (int s = 0; s < 4; s++)
          acc[s] = __builtin_amdgcn_mfma_f32_16x16x32_bf16(a[s][kc], bv[kc], acc[s], 0, 0, 0);
      __builtin_amdgcn_s_setprio(0);
#pragma unroll
      for (int s = 0; s < 4; s++)
#pragma unroll
        for (int r = 0; r < 4; r++) L[s][r] += fexp2(acc[s][r]);
      __builtin_amdgcn_sched_barrier(0);
    }
  };

  // depth-2 prefetch, 1 barrier/tile, counted vmcnt (never 0 until the end)
  STAGE(0);
  STAGE(1);
#pragma unroll 1
  for (int t = 0; t < NT; ++t) {
    if (t < NT - 1) {
      asm volatile("s_waitcnt vmcnt(4)" ::: "memory");   // my tile-t DMAs done
    } else {
      asm volatile("s_waitcnt vmcnt(0)" ::: "memory");
    }
    __builtin_amdgcn_sched_barrier(0);
    __builtin_amdgcn_s_barrier();                        // all waves' tile-t done
    __builtin_amdgcn_sched_barrier(0);
    COMPI(t, t + 2 < NT);
  }

  // reduce across the 16 column-lanes (lanes sharing lq hold the same rows)
#pragma unroll
  for (int s = 0; s < 4; s++)
#pragma unroll
    for (int r = 0; r < 4; r++) {
      float v = L[s][r];
      v += __shfl_xor(v, 1); v += __shfl_xor(v, 2);
      v += __shfl_xor(v, 4); v += __shfl_xor(v, 8);
      if (lr == 0)
        Lp[(size_t)chunk * N2 + rowbase + s * 16 + lq * 4 + r] = v;
    }
}

// ---------------------------------------------------------------------------
// Kernel 3: per-row loss. L_i = sum of 16 partials - exp2(dhat_i);
// target logit from direct bf16 dot; loss_i = ln2*(log2(L_i) - target).
// ---------------------------------------------------------------------------
__global__ __launch_bounds__(256) void krow(const unsigned short* __restrict__ u,
                                            const float* __restrict__ dhat,
                                            const float* __restrict__ Lp,
                                            float* __restrict__ bsum) {
  const int i = blockIdx.x * 256 + threadIdx.x;
  float L = 0.f;
#pragma unroll
  for (int c = 0; c < NCHUNK; c++) L += Lp[(size_t)c * N2 + i];
  L -= fexp2(dhat[i]);   // remove self-similarity term (== diag set to -inf)

  const int j = (i + NHALF) & (N2 - 1);  // positive-pair label
  const unsigned int* ui = (const unsigned int*)(u + (size_t)i * DDIM);
  const unsigned int* uj = (const unsigned int*)(u + (size_t)j * DDIM);
  float dot = 0.f;
#pragma unroll
  for (int k = 0; k < DDIM / 2; k++) {
    unsigned int av = ui[k], bv = uj[k];
    dot += __uint_as_float(av << 16) * __uint_as_float(bv << 16) +
           __uint_as_float(av & 0xffff0000u) * __uint_as_float(bv & 0xffff0000u);
  }
  float loss = LN2F * (flog2(L) - dot);

#pragma unroll
  for (int m = 32; m; m >>= 1) loss += __shfl_xor(loss, m);
  __shared__ float sred[4];
  if ((threadIdx.x & 63) == 0) sred[threadIdx.x >> 6] = loss;
  __syncthreads();
  if (threadIdx.x == 0) bsum[blockIdx.x] = sred[0] + sred[1] + sred[2] + sred[3];
}

// ---------------------------------------------------------------------------
// Kernel 4: final mean over the 32 block partials.
// ---------------------------------------------------------------------------
__global__ void kfinal(const float* __restrict__ bsum, float* __restrict__ out) {
  float v = (threadIdx.x < N2 / 256) ? bsum[threadIdx.x] : 0.f;
#pragma unroll
  for (int m = 32; m; m >>= 1) v += __shfl_xor(v, m);
  if (threadIdx.x == 0) out[0] = v * (1.0f / N2);
}

// ---------------------------------------------------------------------------
// ws layout: u bf16 [8192][128] (2 MB) | dhat f32[8192] (32 KB) |
//            Lp f32[NCHUNK][8192] (512 KB) | bsum f32[32]  -> ~2.6 MB total
// ---------------------------------------------------------------------------
extern "C" void kernel_launch(void* const* d_in, const int* in_sizes, int n_in,
                              void* d_out, int out_size, void* d_ws, size_t ws_size,
                              hipStream_t stream) {
  const float* zi = (const float*)d_in[0];
  const float* zj = (const float*)d_in[1];
  char* ws = (char*)d_ws;
  unsigned short* u = (unsigned short*)ws;
  float* dhat = (float*)(ws + (size_t)N2 * DDIM * 2);
  float* Lp = (float*)(ws + (size_t)N2 * DDIM * 2 + (size_t)N2 * 4);
  float* bsum = (float*)(ws + (size_t)N2 * DDIM * 2 + (size_t)N2 * 4 +
                         (size_t)NCHUNK * N2 * 4);
  float* out = (float*)d_out;

  hipLaunchKernelGGL(knorm, dim3(N2 / 4), dim3(256), 0, stream, zi, zj, u, dhat);
  hipLaunchKernelGGL(ksim, dim3((N2 / 256) * NCHUNK), dim3(256), 0, stream, u, Lp);
  hipLaunchKernelGGL(krow, dim3(N2 / 256), dim3(256), 0, stream, u, dhat, Lp, bsum);
  hipLaunchKernelGGL(kfinal, dim3(1), dim3(64), 0, stream, bsum, out);
}

// Round 18
// 37.542 us; speedup vs baseline: 1.1803x; 1.0746x over previous
//
#include <hip/hip_runtime.h>

#define N2 8192
#define NHALF 4096
#define DDIM 128
#define NCHUNK 16
#define CPC 512           // cols per chunk
#define NT 8              // B-tiles per chunk (512/64)
#define LN2F 0.69314718055994530942f
// SCALEF = sqrt(log2(e)/T) with T=0.5 -> sqrt(2.8853900817779268)
#define SCALEF 1.6986436f

typedef __attribute__((ext_vector_type(8))) short bf8_t;   // 8 bf16 = 4 VGPR
typedef __attribute__((ext_vector_type(4))) float f4_t;    // MFMA C/D frag

__device__ __forceinline__ float fexp2(float x) { return __builtin_amdgcn_exp2f(x); }
__device__ __forceinline__ float flog2(float x) { return __builtin_amdgcn_logf(x); }

__device__ __forceinline__ unsigned short f2bf(float f) {
  unsigned int x = __float_as_uint(f);
  x += 0x7fffu + ((x >> 16) & 1u);   // RNE (no NaN inputs here)
  return (unsigned short)(x >> 16);
}
__device__ __forceinline__ float bf2f(unsigned short h) {
  return __uint_as_float(((unsigned int)h) << 16);
}

// ---------------------------------------------------------------------------
// Kernel 1: normalize rows, scale by sqrt(log2e/T), store bf16 u[8192][128];
// also store dhat[i] = sum_k u_bf16[i][k]^2 (diag logit). Unchanged (passing).
// ---------------------------------------------------------------------------
__global__ __launch_bounds__(256) void knorm(const float* __restrict__ zi,
                                             const float* __restrict__ zj,
                                             unsigned short* __restrict__ u,
                                             float* __restrict__ dhat) {
  const int lane = threadIdx.x & 63;
  const int row = blockIdx.x * 4 + (threadIdx.x >> 6);
  const float* src = (row < NHALF) ? (zi + (size_t)row * DDIM)
                                   : (zj + (size_t)(row - NHALF) * DDIM);
  float2 x = *(const float2*)(src + lane * 2);
  float ss = x.x * x.x + x.y * x.y;
#pragma unroll
  for (int m = 32; m; m >>= 1) ss += __shfl_xor(ss, m);
  float scale = SCALEF / fmaxf(sqrtf(ss), 1e-8f);  // eps clamp as in reference
  unsigned short b0 = f2bf(x.x * scale);
  unsigned short b1 = f2bf(x.y * scale);
  *(unsigned int*)(u + (size_t)row * DDIM + lane * 2) =
      (unsigned int)b0 | ((unsigned int)b1 << 16);
  float f0 = bf2f(b0), f1 = bf2f(b1);
  float dd = f0 * f0 + f1 * f1;
#pragma unroll
  for (int m = 32; m; m >>= 1) dd += __shfl_xor(dd, m);
  if (lane == 0) dhat[row] = dd;
}

// ---------------------------------------------------------------------------
// Kernel 2: fused sim GEMM + per-row sum of exp2 (logits bounded, no max).
// r17 post-mortem: in-tile interleave = null; ksim == SUM of pipe floors
// (~25us) because all waves are phase-locked at 2 waves/SIMD. r18 single
// change vs r14: same WG geometry (256 rows x 512 cols, NT=8, grid 512,
// identical bytes, identical barrier/vmcnt skeleton) but EIGHT 64-thread
// waves per WG, each owning 32 rows via the lean a[2][4]=32-VGPR plan (r3,
// spill-free at VGPR=56). Per-wave VGPR ~75 -> 4 waves/SIMD resident ->
// pipes (MFMA/trans/LDS/DMA) overlap across waves (m114). LDS B-frag reads
// double (accepted: LDS becomes binding pipe ~10us, still << 25).
// Staging mechanics validated r11-r14: lane-contiguous 1KB global_load_lds,
// involution pre-swizzle (16B-unit du of col c at du^(c&7)), 3-ring 48KB,
// depth-2 prefetch, counted vmcnt (2 DMAs/wave/tile -> vmcnt(2) loop-top,
// 0 only at last tile), ONE s_barrier per tile, A gathered once + pinned.
// ---------------------------------------------------------------------------
__global__ __launch_bounds__(512) void ksim(const unsigned short* __restrict__ u,
                                            float* __restrict__ Lp) {
  __shared__ short Bls[24576];  // 48 KB = 3 ring bufs x 16 KB
  const int tid = threadIdx.x;
  const int lane = tid & 63;
  const int w = tid >> 6;                  // 0..7
  const int rb = blockIdx.x >> 4;          // 0..31
  const int chunk = blockIdx.x & 15;       // 0..15
  const int lr = lane & 15, lq = lane >> 4;
  const int rowbase = rb * 256 + w * 32;   // wave's private 32 rows
  const int colbase = chunk * CPC;

  // ---- A: 32 rows per wave, gathered once from global, pinned (lean plan).
  bf8_t a[2][4];
#pragma unroll
  for (int s = 0; s < 2; s++)
#pragma unroll
    for (int kc = 0; kc < 4; kc++)
      a[s][kc] = *(const bf8_t*)(u + (size_t)(rowbase + s * 16 + lr) * DDIM +
                                 kc * 32 + lq * 8);
#pragma unroll
  for (int s = 0; s < 2; s++)
#pragma unroll
    for (int kc = 0; kc < 4; kc++)
      asm volatile("" : "+v"(a[s][kc]));   // forces drain of A loads

  f4_t L0 = {0.f, 0.f, 0.f, 0.f}, L1 = {0.f, 0.f, 0.f, 0.f};

  // ---- B stage: 64-col tile = 16KB = 16 linear 1KB DMAs (2 per wave).
  // LDS unit U holds global du = (U&15)^(col&7); DMA j (= w*2+i), lane l:
  // col_local = j*4+lq, src du = lr^(4*(j&1)+lq).
  auto STAGE = [&](int t) {
#pragma unroll
    for (int i = 0; i < 2; i++) {
      const int j = w * 2 + i;
      const int col_local = j * 4 + lq;
      const int sdu = lr ^ (4 * (j & 1) + lq);
      const unsigned short* src =
          u + (size_t)(colbase + t * 64 + col_local) * DDIM + sdu * 8;
      short* dst = &Bls[(t % 3) * 8192 + j * 512];
      __builtin_amdgcn_global_load_lds(
          (const __attribute__((address_space(1))) unsigned int*)src,
          (__attribute__((address_space(3))) unsigned int*)dst, 16, 0, 0);
    }
  };

  auto COMP = [&](int t) {
    const short* P = &Bls[(t % 3) * 8192];
#pragma unroll
    for (int g = 0; g < 4; g++) {
      bf8_t bv[4];
#pragma unroll
      for (int kc = 0; kc < 4; kc++)
        bv[kc] = *(const bf8_t*)&P[((g * 16 + lr) * 16 +
                                    ((kc * 4 + lq) ^ (lr & 7))) * 8];
      f4_t acc0 = {0.f, 0.f, 0.f, 0.f}, acc1 = {0.f, 0.f, 0.f, 0.f};
#pragma unroll
      for (int kc = 0; kc < 4; kc++) {
        acc0 = __builtin_amdgcn_mfma_f32_16x16x32_bf16(a[0][kc], bv[kc], acc0, 0, 0, 0);
        acc1 = __builtin_amdgcn_mfma_f32_16x16x32_bf16(a[1][kc], bv[kc], acc1, 0, 0, 0);
      }
#pragma unroll
      for (int r = 0; r < 4; r++) {
        L0[r] += fexp2(acc0[r]);
        L1[r] += fexp2(acc1[r]);
      }
    }
  };

  // depth-2 prefetch, 1 barrier/tile, counted vmcnt (never 0 until the end)
  STAGE(0);
  STAGE(1);
#pragma unroll 1
  for (int t = 0; t < NT; ++t) {
    if (t < NT - 1) {
      asm volatile("s_waitcnt vmcnt(2)" ::: "memory");   // my tile-t DMAs done
    } else {
      asm volatile("s_waitcnt vmcnt(0)" ::: "memory");
    }
    __builtin_amdgcn_sched_barrier(0);
    __builtin_amdgcn_s_barrier();                        // all waves' tile-t done
    __builtin_amdgcn_sched_barrier(0);
    COMP(t);
    if (t + 2 < NT) STAGE(t + 2);
  }

  // reduce across the 16 column-lanes (lanes sharing lq hold the same rows)
#pragma unroll
  for (int r = 0; r < 4; r++) {
    float v0 = L0[r], v1 = L1[r];
    v0 += __shfl_xor(v0, 1); v0 += __shfl_xor(v0, 2);
    v0 += __shfl_xor(v0, 4); v0 += __shfl_xor(v0, 8);
    v1 += __shfl_xor(v1, 1); v1 += __shfl_xor(v1, 2);
    v1 += __shfl_xor(v1, 4); v1 += __shfl_xor(v1, 8);
    if (lr == 0) {
      const int rrow = rowbase + lq * 4 + r;
      Lp[(size_t)chunk * N2 + rrow] = v0;        // rows 0-15 of wave strip
      Lp[(size_t)chunk * N2 + rrow + 16] = v1;   // rows 16-31
    }
  }
}

// ---------------------------------------------------------------------------
// Kernel 3: per-row loss. L_i = sum of 16 partials - exp2(dhat_i);
// target logit from direct bf16 dot; loss_i = ln2*(log2(L_i) - target).
// ---------------------------------------------------------------------------
__global__ __launch_bounds__(256) void krow(const unsigned short* __restrict__ u,
                                            const float* __restrict__ dhat,
                                            const float* __restrict__ Lp,
                                            float* __restrict__ bsum) {
  const int i = blockIdx.x * 256 + threadIdx.x;
  float L = 0.f;
#pragma unroll
  for (int c = 0; c < NCHUNK; c++) L += Lp[(size_t)c * N2 + i];
  L -= fexp2(dhat[i]);   // remove self-similarity term (== diag set to -inf)

  const int j = (i + NHALF) & (N2 - 1);  // positive-pair label
  const unsigned int* ui = (const unsigned int*)(u + (size_t)i * DDIM);
  const unsigned int* uj = (const unsigned int*)(u + (size_t)j * DDIM);
  float dot = 0.f;
#pragma unroll
  for (int k = 0; k < DDIM / 2; k++) {
    unsigned int av = ui[k], bv = uj[k];
    dot += __uint_as_float(av << 16) * __uint_as_float(bv << 16) +
           __uint_as_float(av & 0xffff0000u) * __uint_as_float(bv & 0xffff0000u);
  }
  float loss = LN2F * (flog2(L) - dot);

#pragma unroll
  for (int m = 32; m; m >>= 1) loss += __shfl_xor(loss, m);
  __shared__ float sred[4];
  if ((threadIdx.x & 63) == 0) sred[threadIdx.x >> 6] = loss;
  __syncthreads();
  if (threadIdx.x == 0) bsum[blockIdx.x] = sred[0] + sred[1] + sred[2] + sred[3];
}

// ---------------------------------------------------------------------------
// Kernel 4: final mean over the 32 block partials.
// ---------------------------------------------------------------------------
__global__ void kfinal(const float* __restrict__ bsum, float* __restrict__ out) {
  float v = (threadIdx.x < N2 / 256) ? bsum[threadIdx.x] : 0.f;
#pragma unroll
  for (int m = 32; m; m >>= 1) v += __shfl_xor(v, m);
  if (threadIdx.x == 0) out[0] = v * (1.0f / N2);
}

// ---------------------------------------------------------------------------
// ws layout: u bf16 [8192][128] (2 MB) | dhat f32[8192] (32 KB) |
//            Lp f32[NCHUNK][8192] (512 KB) | bsum f32[32]  -> ~2.6 MB total
// ---------------------------------------------------------------------------
extern "C" void kernel_launch(void* const* d_in, const int* in_sizes, int n_in,
                              void* d_out, int out_size, void* d_ws, size_t ws_size,
                              hipStream_t stream) {
  const float* zi = (const float*)d_in[0];
  const float* zj = (const float*)d_in[1];
  char* ws = (char*)d_ws;
  unsigned short* u = (unsigned short*)ws;
  float* dhat = (float*)(ws + (size_t)N2 * DDIM * 2);
  float* Lp = (float*)(ws + (size_t)N2 * DDIM * 2 + (size_t)N2 * 4);
  float* bsum = (float*)(ws + (size_t)N2 * DDIM * 2 + (size_t)N2 * 4 +
                         (size_t)NCHUNK * N2 * 4);
  float* out = (float*)d_out;

  hipLaunchKernelGGL(knorm, dim3(N2 / 4), dim3(256), 0, stream, zi, zj, u, dhat);
  hipLaunchKernelGGL(ksim, dim3((N2 / 256) * NCHUNK), dim3(512), 0, stream, u, Lp);
  hipLaunchKernelGGL(krow, dim3(N2 / 256), dim3(256), 0, stream, u, dhat, Lp, bsum);
  hipLaunchKernelGGL(kfinal, dim3(1), dim3(64), 0, stream, bsum, out);
}

// Round 19
// 36.311 us; speedup vs baseline: 1.2204x; 1.0339x over previous
//
#include <hip/hip_runtime.h>

#define N2 8192
#define NHALF 4096
#define DDIM 128
#define NCHUNK 16
#define CPC 512           // cols per chunk
#define NT 8              // B-tiles per chunk (512/64)
#define RPB 512           // rows per WG (16 waves x 32 rows)
#define LN2F 0.69314718055994530942f
// SCALEF = sqrt(log2(e)/T) with T=0.5 -> sqrt(2.8853900817779268)
#define SCALEF 1.6986436f

typedef __attribute__((ext_vector_type(8))) short bf8_t;   // 8 bf16 = 4 VGPR
typedef __attribute__((ext_vector_type(4))) float f4_t;    // MFMA C/D frag

__device__ __forceinline__ float fexp2(float x) { return __builtin_amdgcn_exp2f(x); }
__device__ __forceinline__ float flog2(float x) { return __builtin_amdgcn_logf(x); }

__device__ __forceinline__ unsigned short f2bf(float f) {
  unsigned int x = __float_as_uint(f);
  x += 0x7fffu + ((x >> 16) & 1u);   // RNE (no NaN inputs here)
  return (unsigned short)(x >> 16);
}
__device__ __forceinline__ float bf2f(unsigned short h) {
  return __uint_as_float(((unsigned int)h) << 16);
}

// ---------------------------------------------------------------------------
// Kernel 1: normalize rows, scale by sqrt(log2e/T), store bf16 u[8192][128];
// also store dhat[i] = sum_k u_bf16[i][k]^2 (diag logit). Unchanged (passing).
// ---------------------------------------------------------------------------
__global__ __launch_bounds__(256) void knorm(const float* __restrict__ zi,
                                             const float* __restrict__ zj,
                                             unsigned short* __restrict__ u,
                                             float* __restrict__ dhat) {
  const int lane = threadIdx.x & 63;
  const int row = blockIdx.x * 4 + (threadIdx.x >> 6);
  const float* src = (row < NHALF) ? (zi + (size_t)row * DDIM)
                                   : (zj + (size_t)(row - NHALF) * DDIM);
  float2 x = *(const float2*)(src + lane * 2);
  float ss = x.x * x.x + x.y * x.y;
#pragma unroll
  for (int m = 32; m; m >>= 1) ss += __shfl_xor(ss, m);
  float scale = SCALEF / fmaxf(sqrtf(ss), 1e-8f);  // eps clamp as in reference
  unsigned short b0 = f2bf(x.x * scale);
  unsigned short b1 = f2bf(x.y * scale);
  *(unsigned int*)(u + (size_t)row * DDIM + lane * 2) =
      (unsigned int)b0 | ((unsigned int)b1 << 16);
  float f0 = bf2f(b0), f1 = bf2f(b1);
  float dd = f0 * f0 + f1 * f1;
#pragma unroll
  for (int m = 32; m; m >>= 1) dd += __shfl_xor(dd, m);
  if (lane == 0) dhat[row] = dd;
}

// ---------------------------------------------------------------------------
// Kernel 2: fused sim GEMM + per-row sum of exp2 (logits bounded, no max).
// r18 post-mortem: 8-wave lean plan helped (+3us); remaining = partial pipe
// convoy + DMA bytes. r19 single ksim change: WG = 512 rows (16 waves x 32
// rows, 1024 thr), grid = 256 = EXACTLY 1 WG/CU, no tail. B staged bytes
// halve (64->32MB total; per-CU DMA 384->192KB). Lean a[2][4] plan (~75
// VGPR < 128 cap for 16 waves/CU). Sync skeleton unchanged: 3-ring 48KB,
// depth-2 prefetch, 1 DMA/wave/tile -> loop-top vmcnt(1), ONE s_barrier per
// tile, vmcnt(0) only at last tile. Staging mechanics validated r11-r18:
// lane-contiguous 1KB global_load_lds, involution pre-swizzle (16B-unit du
// of col c stored at du^(c&7)); swizzled ds_read applies the same XOR.
// Lp layout now [row][16] (chunk minor) so krow's partial read is 1 line.
// ---------------------------------------------------------------------------
__global__ __launch_bounds__(1024) void ksim(const unsigned short* __restrict__ u,
                                             float* __restrict__ Lp) {
  __shared__ short Bls[24576];  // 48 KB = 3 ring bufs x 16 KB
  const int tid = threadIdx.x;
  const int lane = tid & 63;
  const int w = tid >> 6;                  // 0..15
  const int rb = blockIdx.x >> 4;          // 0..15
  const int chunk = blockIdx.x & 15;       // 0..15
  const int lr = lane & 15, lq = lane >> 4;
  const int rowbase = rb * RPB + w * 32;   // wave's private 32 rows
  const int colbase = chunk * CPC;

  // ---- A: 32 rows per wave, gathered once from global, pinned (lean plan).
  bf8_t a[2][4];
#pragma unroll
  for (int s = 0; s < 2; s++)
#pragma unroll
    for (int kc = 0; kc < 4; kc++)
      a[s][kc] = *(const bf8_t*)(u + (size_t)(rowbase + s * 16 + lr) * DDIM +
                                 kc * 32 + lq * 8);
#pragma unroll
  for (int s = 0; s < 2; s++)
#pragma unroll
    for (int kc = 0; kc < 4; kc++)
      asm volatile("" : "+v"(a[s][kc]));   // forces drain of A loads

  f4_t L0 = {0.f, 0.f, 0.f, 0.f}, L1 = {0.f, 0.f, 0.f, 0.f};

  // ---- B stage: 64-col tile = 16KB = 16 linear 1KB DMAs (1 per wave, j=w).
  // LDS unit U holds global du = (U&15)^(col&7); lane l: col_local = w*4+lq,
  // src du = lr^(4*(w&1)+lq).
  auto STAGE = [&](int t) {
    const int col_local = w * 4 + lq;
    const int sdu = lr ^ (4 * (w & 1) + lq);
    const unsigned short* src =
        u + (size_t)(colbase + t * 64 + col_local) * DDIM + sdu * 8;
    short* dst = &Bls[(t % 3) * 8192 + w * 512];
    __builtin_amdgcn_global_load_lds(
        (const __attribute__((address_space(1))) unsigned int*)src,
        (__attribute__((address_space(3))) unsigned int*)dst, 16, 0, 0);
  };

  auto COMP = [&](int t) {
    const short* P = &Bls[(t % 3) * 8192];
#pragma unroll
    for (int g = 0; g < 4; g++) {
      bf8_t bv[4];
#pragma unroll
      for (int kc = 0; kc < 4; kc++)
        bv[kc] = *(const bf8_t*)&P[((g * 16 + lr) * 16 +
                                    ((kc * 4 + lq) ^ (lr & 7))) * 8];
      f4_t acc0 = {0.f, 0.f, 0.f, 0.f}, acc1 = {0.f, 0.f, 0.f, 0.f};
#pragma unroll
      for (int kc = 0; kc < 4; kc++) {
        acc0 = __builtin_amdgcn_mfma_f32_16x16x32_bf16(a[0][kc], bv[kc], acc0, 0, 0, 0);
        acc1 = __builtin_amdgcn_mfma_f32_16x16x32_bf16(a[1][kc], bv[kc], acc1, 0, 0, 0);
      }
#pragma unroll
      for (int r = 0; r < 4; r++) {
        L0[r] += fexp2(acc0[r]);
        L1[r] += fexp2(acc1[r]);
      }
    }
  };

  // depth-2 prefetch, 1 barrier/tile, counted vmcnt (never 0 until the end)
  STAGE(0);
  STAGE(1);
#pragma unroll 1
  for (int t = 0; t < NT; ++t) {
    if (t < NT - 1) {
      asm volatile("s_waitcnt vmcnt(1)" ::: "memory");   // my tile-t DMA done
    } else {
      asm volatile("s_waitcnt vmcnt(0)" ::: "memory");
    }
    __builtin_amdgcn_sched_barrier(0);
    __builtin_amdgcn_s_barrier();                        // all waves' tile-t done
    __builtin_amdgcn_sched_barrier(0);
    COMP(t);
    if (t + 2 < NT) STAGE(t + 2);
  }

  // reduce across the 16 column-lanes; Lp layout [row][16] (chunk minor)
#pragma unroll
  for (int r = 0; r < 4; r++) {
    float v0 = L0[r], v1 = L1[r];
    v0 += __shfl_xor(v0, 1); v0 += __shfl_xor(v0, 2);
    v0 += __shfl_xor(v0, 4); v0 += __shfl_xor(v0, 8);
    v1 += __shfl_xor(v1, 1); v1 += __shfl_xor(v1, 2);
    v1 += __shfl_xor(v1, 4); v1 += __shfl_xor(v1, 8);
    if (lr == 0) {
      const int rrow = rowbase + lq * 4 + r;
      Lp[(size_t)rrow * NCHUNK + chunk] = v0;          // rows 0-15 of strip
      Lp[(size_t)(rrow + 16) * NCHUNK + chunk] = v1;   // rows 16-31
    }
  }
}

// ---------------------------------------------------------------------------
// Kernel 3: per-row loss, wave-per-row (r18 overhead fix: old version ran 32
// blocks = 12% of CUs with a serial 64-iter dot -> latency-bound ~3-4us).
// Lane-parallel dot (64 lanes x 1 dword each) + shuffle reduce; Lp partials
// read as one 64B line by lanes 0-15. grid = 2048 blocks x 256.
// ---------------------------------------------------------------------------
__global__ __launch_bounds__(256) void krow(const unsigned short* __restrict__ u,
                                            const float* __restrict__ dhat,
                                            const float* __restrict__ Lp,
                                            float* __restrict__ bsum) {
  const int lane = threadIdx.x & 63;
  const int w = threadIdx.x >> 6;
  const int i = blockIdx.x * 4 + w;
  const int j = (i + NHALF) & (N2 - 1);  // positive-pair label

  const unsigned int av = ((const unsigned int*)(u + (size_t)i * DDIM))[lane];
  const unsigned int bv = ((const unsigned int*)(u + (size_t)j * DDIM))[lane];
  float dot = __uint_as_float(av << 16) * __uint_as_float(bv << 16) +
              __uint_as_float(av & 0xffff0000u) * __uint_as_float(bv & 0xffff0000u);
  float ls = (lane < NCHUNK) ? Lp[(size_t)i * NCHUNK + lane] : 0.f;
#pragma unroll
  for (int m = 32; m; m >>= 1) {
    dot += __shfl_xor(dot, m);
    ls += __shfl_xor(ls, m);
  }
  __shared__ float sred[4];
  if (lane == 0) {
    const float L = ls - fexp2(dhat[i]);   // remove self-similarity term
    sred[w] = LN2F * (flog2(L) - dot);
  }
  __syncthreads();
  if (threadIdx.x == 0)
    bsum[blockIdx.x] = sred[0] + sred[1] + sred[2] + sred[3];
}

// ---------------------------------------------------------------------------
// Kernel 4: final mean over the 2048 block partials (fixed-order, determin.).
// ---------------------------------------------------------------------------
__global__ void kfinal(const float* __restrict__ bsum, float* __restrict__ out) {
  float v = 0.f;
#pragma unroll
  for (int jj = 0; jj < 32; jj++) v += bsum[threadIdx.x + 64 * jj];
#pragma unroll
  for (int m = 32; m; m >>= 1) v += __shfl_xor(v, m);
  if (threadIdx.x == 0) out[0] = v * (1.0f / N2);
}

// ---------------------------------------------------------------------------
// ws layout: u bf16 [8192][128] (2 MB) | dhat f32[8192] (32 KB) |
//            Lp f32[8192][16] (512 KB) | bsum f32[2048] (8 KB)  -> ~2.6 MB
// ---------------------------------------------------------------------------
extern "C" void kernel_launch(void* const* d_in, const int* in_sizes, int n_in,
                              void* d_out, int out_size, void* d_ws, size_t ws_size,
                              hipStream_t stream) {
  const float* zi = (const float*)d_in[0];
  const float* zj = (const float*)d_in[1];
  char* ws = (char*)d_ws;
  unsigned short* u = (unsigned short*)ws;
  float* dhat = (float*)(ws + (size_t)N2 * DDIM * 2);
  float* Lp = (float*)(ws + (size_t)N2 * DDIM * 2 + (size_t)N2 * 4);
  float* bsum = (float*)(ws + (size_t)N2 * DDIM * 2 + (size_t)N2 * 4 +
                         (size_t)NCHUNK * N2 * 4);
  float* out = (float*)d_out;

  hipLaunchKernelGGL(knorm, dim3(N2 / 4), dim3(256), 0, stream, zi, zj, u, dhat);
  hipLaunchKernelGGL(ksim, dim3((N2 / RPB) * NCHUNK), dim3(1024), 0, stream, u, Lp);
  hipLaunchKernelGGL(krow, dim3(N2 / 4), dim3(256), 0, stream, u, dhat, Lp, bsum);
  hipLaunchKernelGGL(kfinal, dim3(1), dim3(64), 0, stream, bsum, out);
}